// Round 7
// baseline (235.799 us; speedup 1.0000x reference)
//
#include <hip/hip_runtime.h>
#include <hip/hip_bf16.h>

#define N_NODES 100000
#define N_EDGES 3200000
#define F_IN    512
#define F_H     16
#define F_OUT   7
#define NB      391                 // buckets of 256 dst nodes
#define GPART   512                 // partition blocks
#define PER_BLK 6256                // multiple of 4; 512*6256 >= 3.2M (last block short)
#define GEMM_BLKS 782               // 128 rows/block
#define CAPB    10240               // LDS stage cap per bucket (mean 8192, sigma~90)

typedef unsigned int u32;

static __device__ __forceinline__ float bflo(u32 u) { return __uint_as_float(u << 16); }
static __device__ __forceinline__ float bfhi(u32 u) { return __uint_as_float(u & 0xFFFF0000u); }
static __device__ __forceinline__ unsigned short f2bf(float f) {
  u32 x = __float_as_uint(f);
  x += 0x7FFF + ((x >> 16) & 1);    // round-to-nearest-even (finite values)
  return (unsigned short)(x >> 16);
}

// ============ fused: bucket histogram (blocks < GPART) + GEMM1 (rest) ============
__global__ __launch_bounds__(256) void k_hist_gemm1(const int* __restrict__ dst,
                                                    int* __restrict__ hist,
                                                    int* __restrict__ bcnt,
                                                    const float* __restrict__ x,
                                                    const float* __restrict__ W1,
                                                    float* __restrict__ h1) {
  __shared__ __align__(16) char smem[F_H * F_IN * 4];   // 32 KB shared by both paths
  int tid = threadIdx.x;

  if (blockIdx.x < GPART) {
    int* h = (int*)smem;
    for (int b = tid; b < NB; b += 256) h[b] = 0;
    __syncthreads();
    int e0 = blockIdx.x * PER_BLK;
    int n = min(PER_BLK, N_EDGES - e0);          // multiple of 4
    const int4* d4 = (const int4*)(dst + e0);
    for (int i = tid; i < (n >> 2); i += 256) {
      int4 d = d4[i];
      atomicAdd(&h[d.x >> 8], 1);
      atomicAdd(&h[d.y >> 8], 1);
      atomicAdd(&h[d.z >> 8], 1);
      atomicAdd(&h[d.w >> 8], 1);
    }
    __syncthreads();
    for (int b = tid; b < NB; b += 256) {
      int c = h[b];
      hist[blockIdx.x * NB + b] = c;             // block-major per-block counts
      if (c) atomicAdd(&bcnt[b], c);             // bucket totals
    }
    return;
  }

  float* Wt = (float*)smem;                      // [16][512] transposed
  for (int idx = tid; idx < F_IN * F_H; idx += 256) {
    int k = idx >> 4, j = idx & 15;
    Wt[j * F_IN + k] = W1[idx];
  }
  __syncthreads();

  int gb = blockIdx.x - GPART;
  int wave = tid >> 6, lane = tid & 63;
  int g = lane & 7, h = lane >> 3;
  int base = (gb * 4 + wave) * 32;
  int row0 = base + h * 4;

  const float* xp[4];
  bool rv[4];
#pragma unroll
  for (int rr = 0; rr < 4; rr++) {
    int r = row0 + rr;
    rv[rr] = r < N_NODES;
    xp[rr] = x + (size_t)(rv[rr] ? r : 0) * F_IN;
  }

  float acc[4][16];
#pragma unroll
  for (int rr = 0; rr < 4; rr++)
#pragma unroll
    for (int j = 0; j < 16; j++) acc[rr][j] = 0.f;

  for (int t = 0; t < 16; t++) {
    int k0 = g * 4 + t * 32;
    float4 a0 = ((const float4*)xp[0])[g + t * 8];
    float4 a1 = ((const float4*)xp[1])[g + t * 8];
    float4 a2 = ((const float4*)xp[2])[g + t * 8];
    float4 a3 = ((const float4*)xp[3])[g + t * 8];
#pragma unroll
    for (int j = 0; j < 16; j++) {
      float4 wv = *(const float4*)(&Wt[j * F_IN + k0]);
      acc[0][j] += a0.x * wv.x + a0.y * wv.y + a0.z * wv.z + a0.w * wv.w;
      acc[1][j] += a1.x * wv.x + a1.y * wv.y + a1.z * wv.z + a1.w * wv.w;
      acc[2][j] += a2.x * wv.x + a2.y * wv.y + a2.z * wv.z + a2.w * wv.w;
      acc[3][j] += a3.x * wv.x + a3.y * wv.y + a3.z * wv.z + a3.w * wv.w;
    }
  }
#pragma unroll
  for (int off = 1; off < 8; off <<= 1)
#pragma unroll
    for (int rr = 0; rr < 4; rr++)
#pragma unroll
      for (int j = 0; j < 16; j++)
        acc[rr][j] += __shfl_xor(acc[rr][j], off, 64);

  if (g == 0) {
#pragma unroll
    for (int rr = 0; rr < 4; rr++) {
      if (!rv[rr]) continue;
      float4* o = (float4*)(h1 + (size_t)(row0 + rr) * F_H);
      o[0] = make_float4(acc[rr][0], acc[rr][1], acc[rr][2], acc[rr][3]);
      o[1] = make_float4(acc[rr][4], acc[rr][5], acc[rr][6], acc[rr][7]);
      o[2] = make_float4(acc[rr][8], acc[rr][9], acc[rr][10], acc[rr][11]);
      o[3] = make_float4(acc[rr][12], acc[rr][13], acc[rr][14], acc[rr][15]);
    }
  }
}

// -------- single tiny scan: bucket bases + gcur init + rowptr sentinel --------
__global__ __launch_bounds__(512) void k_scan391(const int* __restrict__ bcnt,
                                                 int* __restrict__ pbase,
                                                 int* __restrict__ gcur,
                                                 int* __restrict__ rowptr) {
  __shared__ int lds[512];
  int tid = threadIdx.x;
  int c = (tid < NB) ? bcnt[tid] : 0;
  lds[tid] = c;
  __syncthreads();
  for (int off = 1; off < 512; off <<= 1) {
    int v = (tid >= off) ? lds[tid - off] : 0;
    __syncthreads();
    lds[tid] += v;
    __syncthreads();
  }
  int ex = lds[tid] - c;
  if (tid <= NB) pbase[tid] = ex;     // pbase[NB] == N_EDGES (total)
  if (tid < NB) gcur[tid] = ex;
  if (tid == 0) rowptr[N_NODES] = N_EDGES;
}

// -------- partition scatter: reserve ranges atomically, LDS cursors --------
// pack: (dst_local << 17) | src
__global__ __launch_bounds__(256) void k_part(const int* __restrict__ src,
                                              const int* __restrict__ dst,
                                              const int* __restrict__ hist,
                                              int* __restrict__ gcur,
                                              u32* __restrict__ pairs) {
  __shared__ int lbase[NB];
  __shared__ int lcur[NB];
  int tid = threadIdx.x, blk = blockIdx.x;
  for (int b = tid; b < NB; b += 256) {
    int c = hist[blk * NB + b];
    lbase[b] = c ? atomicAdd(&gcur[b], c) : 0;
    lcur[b] = 0;
  }
  __syncthreads();
  int e0 = blk * PER_BLK;
  int n = min(PER_BLK, N_EDGES - e0);            // multiple of 4
  const int4* s4 = (const int4*)(src + e0);
  const int4* d4 = (const int4*)(dst + e0);
  for (int i = tid; i < (n >> 2); i += 256) {
    int4 sv = s4[i];
    int4 dv = d4[i];
    { int b = dv.x >> 8; u32 v = ((u32)(dv.x & 255) << 17) | (u32)sv.x;
      pairs[lbase[b] + atomicAdd(&lcur[b], 1)] = v; }
    { int b = dv.y >> 8; u32 v = ((u32)(dv.y & 255) << 17) | (u32)sv.y;
      pairs[lbase[b] + atomicAdd(&lcur[b], 1)] = v; }
    { int b = dv.z >> 8; u32 v = ((u32)(dv.z & 255) << 17) | (u32)sv.z;
      pairs[lbase[b] + atomicAdd(&lcur[b], 1)] = v; }
    { int b = dv.w >> 8; u32 v = ((u32)(dv.w & 255) << 17) | (u32)sv.w;
      pairs[lbase[b] + atomicAdd(&lcur[b], 1)] = v; }
  }
}

// ---- per-bucket CSR (pairs staged in LDS, read once) + rowptr + h1p fold ----
__global__ __launch_bounds__(512) void k_bcsr(const u32* __restrict__ pairs,
                                              const int* __restrict__ pbase,
                                              int* __restrict__ colsrc,
                                              int* __restrict__ rowptr,
                                              const float* __restrict__ h1,
                                              unsigned short* __restrict__ h1p) {
  __shared__ u32 stage[CAPB];                    // 40 KB
  __shared__ int hist256[256];
  __shared__ int scan_[256];
  __shared__ int excl[256];
  __shared__ int cur[256];
  __shared__ float sdinv[256];
  int tid = threadIdx.x, b = blockIdx.x;
  if (tid < 256) { hist256[tid] = 0; cur[tid] = 0; }
  __syncthreads();
  int base = pbase[b];
  int cnt  = pbase[b + 1] - base;
  for (int k = tid; k < cnt; k += 512) {
    u32 v = pairs[base + k];
    if (k < CAPB) stage[k] = v;
    atomicAdd(&hist256[v >> 17], 1);
  }
  __syncthreads();
  if (tid < 256) scan_[tid] = hist256[tid];
  __syncthreads();
  for (int off = 1; off < 256; off <<= 1) {
    int v = 0;
    if (tid < 256 && tid >= off) v = scan_[tid - off];
    __syncthreads();
    if (tid < 256) scan_[tid] += v;
    __syncthreads();
  }
  if (tid < 256) {
    int c = hist256[tid];
    int ex = scan_[tid] - c;
    excl[tid] = ex;
    sdinv[tid] = rsqrtf((float)(c + 1));
    int node = b * 256 + tid;
    if (node < N_NODES) rowptr[node] = base + ex;
  }
  __syncthreads();
  for (int k = tid; k < cnt; k += 512) {
    u32 v = (k < CAPB) ? stage[k] : pairs[base + k];
    int dl = v >> 17;
    colsrc[base + excl[dl] + atomicAdd(&cur[dl], 1)] = (int)(v & 0x1FFFF);
  }
  // epilogue: h1p = bf16(dinv * h1) for this bucket's nodes
  int nmax = min(256, N_NODES - b * 256);
  for (int idx = tid; idx < nmax * 16; idx += 512) {
    int ln = idx >> 4, j = idx & 15;
    size_t n = (size_t)(b * 256 + ln);
    h1p[n * 16 + j] = f2bf(h1[n * 16 + j] * sdinv[ln]);
  }
}

// ======= fused agg1 (+bias+ReLU) + GEMM2 -> gfp bf16[N][8]; dinv folded =======
// wave per node: f = lane&7 (uint = 2 feats of 32B row), q = lane>>3 (8 slots)
__global__ __launch_bounds__(256) void k_agg1g2(const unsigned short* __restrict__ h1p,
                                                const int* __restrict__ colsrc,
                                                const int* __restrict__ rowptr,
                                                const float* __restrict__ b1,
                                                const float* __restrict__ W2,
                                                unsigned short* __restrict__ gfp) {
  int tid = threadIdx.x;
  int wv = tid >> 6, lane = tid & 63;
  int f = lane & 7, q = lane >> 3;
  int i = blockIdx.x * 4 + wv;                   // exact grid: 25000 blocks

  bool jv = f < 7;
  float wcol[16];
#pragma unroll
  for (int k = 0; k < 16; k++) wcol[k] = jv ? W2[k * 7 + f] : 0.f;
  float bb0 = b1[2 * f], bb1 = b1[2 * f + 1];

  int start = rowptr[i];
  int cnt = rowptr[i + 1] - start;
  float a0 = 0.f, a1 = 0.f;
  const u32* hp = (const u32*)h1p;               // row i -> 8 uints at i*8
  for (int e = q; e < cnt; e += 8) {
    int src = colsrc[start + e];
    u32 hv = hp[src * 8 + f];
    a0 += bflo(hv); a1 += bfhi(hv);
  }
  if (q == 0) {                                  // self-loop (dinv pre-folded)
    u32 hv = hp[i * 8 + f];
    a0 += bflo(hv); a1 += bfhi(hv);
  }
#pragma unroll
  for (int off = 8; off < 64; off <<= 1) {
    a0 += __shfl_xor(a0, off, 64);
    a1 += __shfl_xor(a1, off, 64);
  }
  float di = rsqrtf((float)(cnt + 1));
  float v0 = fmaxf(di * a0 + bb0, 0.f);
  float v1 = fmaxf(di * a1 + bb1, 0.f);

  // W2 dot: gather the 16 h2 features from this lane's 8-lane group
  int baseLane = lane & ~7;
  float o = 0.f;
#pragma unroll
  for (int f2 = 0; f2 < 8; f2++) {
    float u0 = __shfl(v0, baseLane + f2, 64);
    float u1 = __shfl(v1, baseLane + f2, 64);
    o += u0 * wcol[2 * f2] + u1 * wcol[2 * f2 + 1];
  }
  if (lane < 8) gfp[(size_t)i * 8 + f] = jv ? f2bf(di * o) : (unsigned short)0;
}

// ============ agg2 + bias + log_softmax -> out [N,7] ============
// wave per node: f = lane&3 (uint = 2 feats of 16B row), q = lane>>2 (16 slots)
__global__ __launch_bounds__(256) void k_agg2(const unsigned short* __restrict__ gfp,
                                              const int* __restrict__ colsrc,
                                              const int* __restrict__ rowptr,
                                              const float* __restrict__ b2,
                                              float* __restrict__ out) {
  int tid = threadIdx.x;
  int wv = tid >> 6, lane = tid & 63;
  int f = lane & 3, q = lane >> 2;
  int i = blockIdx.x * 4 + wv;                   // exact grid

  int j0 = 2 * f, j1 = 2 * f + 1;
  float bb0 = b2[j0], bb1 = (j1 < 7) ? b2[j1] : 0.f;

  int start = rowptr[i];
  int cnt = rowptr[i + 1] - start;
  float a0 = 0.f, a1 = 0.f;
  const u32* gp = (const u32*)gfp;               // row i -> 4 uints at i*4
  for (int e = q; e < cnt; e += 16) {
    int src = colsrc[start + e];
    u32 gv = gp[src * 4 + f];
    a0 += bflo(gv); a1 += bfhi(gv);
  }
  if (q == 0) {                                  // self-loop
    u32 gv = gp[i * 4 + f];
    a0 += bflo(gv); a1 += bfhi(gv);
  }
#pragma unroll
  for (int off = 4; off < 64; off <<= 1) {
    a0 += __shfl_xor(a0, off, 64);
    a1 += __shfl_xor(a1, off, 64);
  }
  float di = rsqrtf((float)(cnt + 1));
  float v0 = di * a0 + bb0;
  float v1 = (j1 < 7) ? (di * a1 + bb1) : -1e30f;

  float m = fmaxf(v0, v1);
  m = fmaxf(m, __shfl_xor(m, 1, 64));
  m = fmaxf(m, __shfl_xor(m, 2, 64));
  float s = __expf(v0 - m) + ((j1 < 7) ? __expf(v1 - m) : 0.f);
  s += __shfl_xor(s, 1, 64);
  s += __shfl_xor(s, 2, 64);
  float ls = logf(s);
  if (lane < 4) {
    out[(size_t)i * 7 + j0] = v0 - m - ls;
    if (j1 < 7) out[(size_t)i * 7 + j1] = v1 - m - ls;
  }
}

extern "C" void kernel_launch(void* const* d_in, const int* in_sizes, int n_in,
                              void* d_out, int out_size, void* d_ws, size_t ws_size,
                              hipStream_t stream) {
  const float* x  = (const float*)d_in[0];
  const int*   ei = (const int*)d_in[1];     // [0..E)=src, [E..2E)=dst (int32)
  const float* W1 = (const float*)d_in[2];
  const float* b1 = (const float*)d_in[3];
  const float* W2 = (const float*)d_in[4];
  const float* b2 = (const float*)d_in[5];
  float* out = (float*)d_out;

  // workspace layout (~38 MB; d_ws ~800 MB)
  char* base = (char*)d_ws;
  int*   bcnt   = (int*)(base + 0);            //      2,048 (392*4 used)
  int*   pbase  = (int*)(base + 2048);         //      2,048 (392*4 used)
  int*   gcur   = (int*)(base + 4096);         //      2,048
  int*   rowptr = (int*)(base + 6144);         //    400,128 (N+1 used)
  int*   hist   = (int*)(base + 406272);       //    800,768 (GPART*NB*4)
  int*   colsrc = (int*)(base + 1207040);      // 12.8 MB  (ends 14,007,040)
  u32*   pairs  = (u32*)(base + 14007040);     // 12.8 MB  (ends 26,807,040)
  float* h1     = (float*)(base + 26807040);   //  6.4 MB  (ends 33,207,040)
  unsigned short* h1p = (unsigned short*)(base + 33207040); // 3.2 MB (ends 36,407,040)
  unsigned short* gfp = (unsigned short*)(base + 36407040); // 1.6 MB (ends 38,007,040)

  hipMemsetAsync(bcnt, 0, 2048, stream);

  k_hist_gemm1<<<GPART + GEMM_BLKS, 256, 0, stream>>>(ei + N_EDGES, hist, bcnt, x, W1, h1);
  k_scan391   <<<1, 512, 0, stream>>>(bcnt, pbase, gcur, rowptr);
  k_part      <<<GPART, 256, 0, stream>>>(ei, ei + N_EDGES, hist, gcur, pairs);
  k_bcsr      <<<NB, 512, 0, stream>>>(pairs, pbase, colsrc, rowptr, h1, h1p);
  k_agg1g2    <<<N_NODES / 4, 256, 0, stream>>>(h1p, colsrc, rowptr, b1, W2, gfp);
  k_agg2      <<<N_NODES / 4, 256, 0, stream>>>(gfp, colsrc, rowptr, b2, out);
}

// Round 8
// 228.343 us; speedup vs baseline: 1.0327x; 1.0327x over previous
//
#include <hip/hip_runtime.h>
#include <hip/hip_bf16.h>

#define N_NODES 100000
#define N_EDGES 3200000
#define F_IN    512
#define F_H     16
#define F_OUT   7
#define NB      391                 // buckets of 256 dst nodes
#define GPART   512                 // partition blocks
#define PER_BLK 6256                // multiple of 4; 512*6256 >= 3.2M (last block short)
#define GEMM_BLKS 782               // 128 rows/block
#define CAPB    10240               // LDS stage cap per bucket (mean 8184, sigma~90)
#define WTS     516                 // padded Wt stride (floats): %4==0, (j*4)%32 2-way max

typedef unsigned int u32;

static __device__ __forceinline__ float bflo(u32 u) { return __uint_as_float(u << 16); }
static __device__ __forceinline__ float bfhi(u32 u) { return __uint_as_float(u & 0xFFFF0000u); }
static __device__ __forceinline__ unsigned short f2bf(float f) {
  u32 x = __float_as_uint(f);
  x += 0x7FFF + ((x >> 16) & 1);    // round-to-nearest-even (finite values)
  return (unsigned short)(x >> 16);
}

// ============ fused: bucket histogram (blocks < GPART) + GEMM1 (rest) ============
// __launch_bounds__(256,2): VGPR cap 256 so acc[4][16] + pipelined loads stay
// in registers (the default heuristic capped at 72 -> scratch spills -> 116us).
__global__ __launch_bounds__(256, 2) void k_hist_gemm1(const int* __restrict__ dst,
                                                       int* __restrict__ hist,
                                                       int* __restrict__ bcnt,
                                                       const float* __restrict__ x,
                                                       const float* __restrict__ W1,
                                                       float* __restrict__ h1) {
  __shared__ __align__(16) float smem[F_H * WTS];   // 33 KB shared by both paths
  int tid = threadIdx.x;

  if (blockIdx.x < GPART) {
    int* h = (int*)smem;
    for (int b = tid; b < NB; b += 256) h[b] = 0;
    __syncthreads();
    int e0 = blockIdx.x * PER_BLK;
    int n = min(PER_BLK, N_EDGES - e0);          // multiple of 4
    const int4* d4 = (const int4*)(dst + e0);
    for (int i = tid; i < (n >> 2); i += 256) {
      int4 d = d4[i];
      atomicAdd(&h[d.x >> 8], 1);
      atomicAdd(&h[d.y >> 8], 1);
      atomicAdd(&h[d.z >> 8], 1);
      atomicAdd(&h[d.w >> 8], 1);
    }
    __syncthreads();
    for (int b = tid; b < NB; b += 256) {
      int c = h[b];
      hist[blockIdx.x * NB + b] = c;             // block-major per-block counts
      if (c) atomicAdd(&bcnt[b], c);             // bucket totals
    }
    return;
  }

  float* Wt = smem;                              // [16][WTS] transposed, padded
  for (int idx = tid; idx < F_IN * F_H; idx += 256) {
    int k = idx >> 4, j = idx & 15;
    Wt[j * WTS + k] = W1[idx];
  }
  __syncthreads();

  int gb = blockIdx.x - GPART;
  int wave = tid >> 6, lane = tid & 63;
  int g = lane & 7, h = lane >> 3;
  int base = (gb * 4 + wave) * 32;
  int row0 = base + h * 4;

  const float* xp[4];
  bool rv[4];
#pragma unroll
  for (int rr = 0; rr < 4; rr++) {
    int r = row0 + rr;
    rv[rr] = r < N_NODES;
    xp[rr] = x + (size_t)(rv[rr] ? r : 0) * F_IN;
  }

  float acc[4][16];
#pragma unroll
  for (int rr = 0; rr < 4; rr++)
#pragma unroll
    for (int j = 0; j < 16; j++) acc[rr][j] = 0.f;

#pragma unroll 2
  for (int t = 0; t < 16; t++) {
    int k0 = g * 4 + t * 32;
    float4 a0 = ((const float4*)xp[0])[g + t * 8];
    float4 a1 = ((const float4*)xp[1])[g + t * 8];
    float4 a2 = ((const float4*)xp[2])[g + t * 8];
    float4 a3 = ((const float4*)xp[3])[g + t * 8];
#pragma unroll
    for (int j = 0; j < 16; j++) {
      float4 wv = *(const float4*)(&Wt[j * WTS + k0]);
      acc[0][j] += a0.x * wv.x + a0.y * wv.y + a0.z * wv.z + a0.w * wv.w;
      acc[1][j] += a1.x * wv.x + a1.y * wv.y + a1.z * wv.z + a1.w * wv.w;
      acc[2][j] += a2.x * wv.x + a2.y * wv.y + a2.z * wv.z + a2.w * wv.w;
      acc[3][j] += a3.x * wv.x + a3.y * wv.y + a3.z * wv.z + a3.w * wv.w;
    }
  }
#pragma unroll
  for (int off = 1; off < 8; off <<= 1)
#pragma unroll
    for (int rr = 0; rr < 4; rr++)
#pragma unroll
      for (int j = 0; j < 16; j++)
        acc[rr][j] += __shfl_xor(acc[rr][j], off, 64);

  if (g == 0) {
#pragma unroll
    for (int rr = 0; rr < 4; rr++) {
      if (!rv[rr]) continue;
      float4* o = (float4*)(h1 + (size_t)(row0 + rr) * F_H);
      o[0] = make_float4(acc[rr][0], acc[rr][1], acc[rr][2], acc[rr][3]);
      o[1] = make_float4(acc[rr][4], acc[rr][5], acc[rr][6], acc[rr][7]);
      o[2] = make_float4(acc[rr][8], acc[rr][9], acc[rr][10], acc[rr][11]);
      o[3] = make_float4(acc[rr][12], acc[rr][13], acc[rr][14], acc[rr][15]);
    }
  }
}

// -------- single tiny scan: bucket bases + gcur init + rowptr sentinel --------
__global__ __launch_bounds__(512) void k_scan391(const int* __restrict__ bcnt,
                                                 int* __restrict__ pbase,
                                                 int* __restrict__ gcur,
                                                 int* __restrict__ rowptr) {
  __shared__ int lds[512];
  int tid = threadIdx.x;
  int c = (tid < NB) ? bcnt[tid] : 0;
  lds[tid] = c;
  __syncthreads();
  for (int off = 1; off < 512; off <<= 1) {
    int v = (tid >= off) ? lds[tid - off] : 0;
    __syncthreads();
    lds[tid] += v;
    __syncthreads();
  }
  int ex = lds[tid] - c;
  if (tid <= NB) pbase[tid] = ex;     // pbase[NB] == N_EDGES (total)
  if (tid < NB) gcur[tid] = ex;
  if (tid == 0) rowptr[N_NODES] = N_EDGES;
}

// -------- partition scatter: reserve ranges atomically, LDS cursors --------
// pack: (dst_local << 17) | src
__global__ __launch_bounds__(256) void k_part(const int* __restrict__ src,
                                              const int* __restrict__ dst,
                                              const int* __restrict__ hist,
                                              int* __restrict__ gcur,
                                              u32* __restrict__ pairs) {
  __shared__ int lbase[NB];
  __shared__ int lcur[NB];
  int tid = threadIdx.x, blk = blockIdx.x;
  for (int b = tid; b < NB; b += 256) {
    int c = hist[blk * NB + b];
    lbase[b] = c ? atomicAdd(&gcur[b], c) : 0;
    lcur[b] = 0;
  }
  __syncthreads();
  int e0 = blk * PER_BLK;
  int n = min(PER_BLK, N_EDGES - e0);            // multiple of 4
  const int4* s4 = (const int4*)(src + e0);
  const int4* d4 = (const int4*)(dst + e0);
  for (int i = tid; i < (n >> 2); i += 256) {
    int4 sv = s4[i];
    int4 dv = d4[i];
    { int b = dv.x >> 8; u32 v = ((u32)(dv.x & 255) << 17) | (u32)sv.x;
      pairs[lbase[b] + atomicAdd(&lcur[b], 1)] = v; }
    { int b = dv.y >> 8; u32 v = ((u32)(dv.y & 255) << 17) | (u32)sv.y;
      pairs[lbase[b] + atomicAdd(&lcur[b], 1)] = v; }
    { int b = dv.z >> 8; u32 v = ((u32)(dv.z & 255) << 17) | (u32)sv.z;
      pairs[lbase[b] + atomicAdd(&lcur[b], 1)] = v; }
    { int b = dv.w >> 8; u32 v = ((u32)(dv.w & 255) << 17) | (u32)sv.w;
      pairs[lbase[b] + atomicAdd(&lcur[b], 1)] = v; }
  }
}

// ---- per-bucket CSR (pairs staged in LDS, read once) + rowptr + h1p fold ----
__global__ __launch_bounds__(512) void k_bcsr(const u32* __restrict__ pairs,
                                              const int* __restrict__ pbase,
                                              int* __restrict__ colsrc,
                                              int* __restrict__ rowptr,
                                              const float* __restrict__ h1,
                                              unsigned short* __restrict__ h1p) {
  __shared__ u32 stage[CAPB];                    // 40 KB
  __shared__ int hist256[256];
  __shared__ int scan_[256];
  __shared__ int excl[256];
  __shared__ int cur[256];
  __shared__ float sdinv[256];
  int tid = threadIdx.x, b = blockIdx.x;
  if (tid < 256) { hist256[tid] = 0; cur[tid] = 0; }
  __syncthreads();
  int base = pbase[b];
  int cnt  = pbase[b + 1] - base;
  for (int k = tid; k < cnt; k += 512) {
    u32 v = pairs[base + k];
    if (k < CAPB) stage[k] = v;
    atomicAdd(&hist256[v >> 17], 1);
  }
  __syncthreads();
  if (tid < 256) scan_[tid] = hist256[tid];
  __syncthreads();
  for (int off = 1; off < 256; off <<= 1) {
    int v = 0;
    if (tid < 256 && tid >= off) v = scan_[tid - off];
    __syncthreads();
    if (tid < 256) scan_[tid] += v;
    __syncthreads();
  }
  if (tid < 256) {
    int c = hist256[tid];
    int ex = scan_[tid] - c;
    excl[tid] = ex;
    sdinv[tid] = rsqrtf((float)(c + 1));
    int node = b * 256 + tid;
    if (node < N_NODES) rowptr[node] = base + ex;
  }
  __syncthreads();
  for (int k = tid; k < cnt; k += 512) {
    u32 v = (k < CAPB) ? stage[k] : pairs[base + k];
    int dl = v >> 17;
    colsrc[base + excl[dl] + atomicAdd(&cur[dl], 1)] = (int)(v & 0x1FFFF);
  }
  // epilogue: h1p = bf16(dinv * h1) for this bucket's nodes
  int nmax = min(256, N_NODES - b * 256);
  for (int idx = tid; idx < nmax * 16; idx += 512) {
    int ln = idx >> 4, j = idx & 15;
    size_t n = (size_t)(b * 256 + ln);
    h1p[n * 16 + j] = f2bf(h1[n * 16 + j] * sdinv[ln]);
  }
}

// ======= fused agg1 (+bias+ReLU) + GEMM2 -> gfp bf16[N][8]; dinv folded =======
// wave per node: c = lane&1 (uint4 = 8 feats of 32B row), q = lane>>1 (32 slots)
__global__ __launch_bounds__(256) void k_agg1g2(const unsigned short* __restrict__ h1p,
                                                const int* __restrict__ colsrc,
                                                const int* __restrict__ rowptr,
                                                const float* __restrict__ b1,
                                                const float* __restrict__ W2,
                                                unsigned short* __restrict__ gfp) {
  int tid = threadIdx.x;
  int wv = tid >> 6, lane = tid & 63;
  int c = lane & 1, q = lane >> 1;
  int i = blockIdx.x * 4 + wv;                   // exact grid: 25000 blocks

  int jp = lane & 7;
  bool jv = jp < 7;
  float wcol[16];
#pragma unroll
  for (int k = 0; k < 16; k++) wcol[k] = jv ? W2[k * 7 + jp] : 0.f;

  int start = rowptr[i];
  int cnt = rowptr[i + 1] - start;
  float acc[8];
#pragma unroll
  for (int k = 0; k < 8; k++) acc[k] = 0.f;

  const uint4* hp = (const uint4*)h1p;           // row i -> units i*2 + c
  for (int e = q; e < cnt; e += 32) {
    int src = colsrc[start + e];
    uint4 hv = hp[src * 2 + c];
    acc[0] += bflo(hv.x); acc[1] += bfhi(hv.x);
    acc[2] += bflo(hv.y); acc[3] += bfhi(hv.y);
    acc[4] += bflo(hv.z); acc[5] += bfhi(hv.z);
    acc[6] += bflo(hv.w); acc[7] += bfhi(hv.w);
  }
  if (q == 0) {                                  // self-loop (dinv pre-folded)
    uint4 hv = hp[i * 2 + c];
    acc[0] += bflo(hv.x); acc[1] += bfhi(hv.x);
    acc[2] += bflo(hv.y); acc[3] += bfhi(hv.y);
    acc[4] += bflo(hv.z); acc[5] += bfhi(hv.z);
    acc[6] += bflo(hv.w); acc[7] += bfhi(hv.w);
  }
#pragma unroll
  for (int off = 2; off < 64; off <<= 1)
#pragma unroll
    for (int k = 0; k < 8; k++) acc[k] += __shfl_xor(acc[k], off, 64);

  // bias + ReLU on own half (feats c*8 + k), dinv recomputed
  float di = rsqrtf((float)(cnt + 1));
  float own[8], oth[8];
#pragma unroll
  for (int k = 0; k < 8; k++)
    own[k] = fmaxf(di * acc[k] + b1[c * 8 + k], 0.f);
  // exchange halves with the c-partner lane (xor 1)
#pragma unroll
  for (int k = 0; k < 8; k++) oth[k] = __shfl_xor(own[k], 1, 64);

  // full h2 row in order: j<8 from (c==0?own:oth), j>=8 from (c==0?oth:own)
  float o = 0.f;
#pragma unroll
  for (int k = 0; k < 8; k++) {
    float lo8 = (c == 0) ? own[k] : oth[k];
    float hi8 = (c == 0) ? oth[k] : own[k];
    o += lo8 * wcol[k] + hi8 * wcol[8 + k];
  }
  if (lane < 8) gfp[(size_t)i * 8 + jp] = jv ? f2bf(di * o) : (unsigned short)0;
}

// ============ agg2 + bias + log_softmax -> out [N,7] ============
// wave per node: c = lane&1 (uint2 = 4 feats of 16B row), q = lane>>1 (32 slots)
__global__ __launch_bounds__(256) void k_agg2(const unsigned short* __restrict__ gfp,
                                              const int* __restrict__ colsrc,
                                              const int* __restrict__ rowptr,
                                              const float* __restrict__ b2,
                                              float* __restrict__ out) {
  int tid = threadIdx.x;
  int wv = tid >> 6, lane = tid & 63;
  int c = lane & 1, q = lane >> 1;
  int i = blockIdx.x * 4 + wv;                   // exact grid

  int start = rowptr[i];
  int cnt = rowptr[i + 1] - start;
  float acc[4] = {0.f, 0.f, 0.f, 0.f};
  const uint2* gp = (const uint2*)gfp;           // row i -> units i*2 + c
  for (int e = q; e < cnt; e += 32) {
    int src = colsrc[start + e];
    uint2 gv = gp[src * 2 + c];
    acc[0] += bflo(gv.x); acc[1] += bfhi(gv.x);
    acc[2] += bflo(gv.y); acc[3] += bfhi(gv.y);
  }
  if (q == 0) {                                  // self-loop
    uint2 gv = gp[i * 2 + c];
    acc[0] += bflo(gv.x); acc[1] += bfhi(gv.x);
    acc[2] += bflo(gv.y); acc[3] += bfhi(gv.y);
  }
#pragma unroll
  for (int off = 2; off < 64; off <<= 1)
#pragma unroll
    for (int k = 0; k < 4; k++) acc[k] += __shfl_xor(acc[k], off, 64);

  float di = rsqrtf((float)(cnt + 1));
  float v[4];
#pragma unroll
  for (int k = 0; k < 4; k++) {
    int f = c * 4 + k;
    v[k] = (f < 7) ? (di * acc[k] + b2[f]) : -1e30f;
  }
  float m = fmaxf(fmaxf(v[0], v[1]), fmaxf(v[2], v[3]));
  m = fmaxf(m, __shfl_xor(m, 1, 64));
  float s = __expf(v[0] - m) + __expf(v[1] - m) + __expf(v[2] - m) + __expf(v[3] - m);
  s += __shfl_xor(s, 1, 64);
  float ls = logf(s);
  if (q == 0) {
#pragma unroll
    for (int k = 0; k < 4; k++) {
      int f = c * 4 + k;
      if (f < 7) out[(size_t)i * 7 + f] = v[k] - m - ls;
    }
  }
}

extern "C" void kernel_launch(void* const* d_in, const int* in_sizes, int n_in,
                              void* d_out, int out_size, void* d_ws, size_t ws_size,
                              hipStream_t stream) {
  const float* x  = (const float*)d_in[0];
  const int*   ei = (const int*)d_in[1];     // [0..E)=src, [E..2E)=dst (int32)
  const float* W1 = (const float*)d_in[2];
  const float* b1 = (const float*)d_in[3];
  const float* W2 = (const float*)d_in[4];
  const float* b2 = (const float*)d_in[5];
  float* out = (float*)d_out;

  // workspace layout (~38 MB; d_ws ~800 MB)
  char* base = (char*)d_ws;
  int*   bcnt   = (int*)(base + 0);            //      2,048 (392*4 used)
  int*   pbase  = (int*)(base + 2048);         //      2,048 (392*4 used)
  int*   gcur   = (int*)(base + 4096);         //      2,048
  int*   rowptr = (int*)(base + 6144);         //    400,128 (N+1 used)
  int*   hist   = (int*)(base + 406272);       //    800,768 (GPART*NB*4)
  int*   colsrc = (int*)(base + 1207040);      // 12.8 MB  (ends 14,007,040)
  u32*   pairs  = (u32*)(base + 14007040);     // 12.8 MB  (ends 26,807,040)
  float* h1     = (float*)(base + 26807040);   //  6.4 MB  (ends 33,207,040)
  unsigned short* h1p = (unsigned short*)(base + 33207040); // 3.2 MB (ends 36,407,040)
  unsigned short* gfp = (unsigned short*)(base + 36407040); // 1.6 MB (ends 38,007,040)

  hipMemsetAsync(bcnt, 0, 2048, stream);

  k_hist_gemm1<<<GPART + GEMM_BLKS, 256, 0, stream>>>(ei + N_EDGES, hist, bcnt, x, W1, h1);
  k_scan391   <<<1, 512, 0, stream>>>(bcnt, pbase, gcur, rowptr);
  k_part      <<<GPART, 256, 0, stream>>>(ei, ei + N_EDGES, hist, gcur, pairs);
  k_bcsr      <<<NB, 512, 0, stream>>>(pairs, pbase, colsrc, rowptr, h1, h1p);
  k_agg1g2    <<<N_NODES / 4, 256, 0, stream>>>(h1p, colsrc, rowptr, b1, W2, gfp);
  k_agg2      <<<N_NODES / 4, 256, 0, stream>>>(gfp, colsrc, rowptr, b2, out);
}